// Round 7
// baseline (704.035 us; speedup 1.0000x reference)
//
#include <hip/hip_runtime.h>
#include <stdint.h>

// ---------------------------------------------------------------------------
// AdaptiveDiffAttention on MI355X (gfx950)
// Round 7: fp8(e4m3) scores path. Q1/K1/Q2/K2 projections computed and stored
// in fp8 (x_f8 @ w_f8 -> qk8), V/WO/lambda stay bf16. GEMM structure = r4's
// best (4-phase loose-fence, counted vmcnt, byte-identical stage ledger).
// ---------------------------------------------------------------------------

#define BATCH  16384
#define ATT_SCALE 0.0625f // 256^-0.5

typedef __attribute__((ext_vector_type(8)))  short   s16x8;
typedef __attribute__((ext_vector_type(4)))  float   f32x4;
typedef __attribute__((ext_vector_type(8)))  unsigned short u16x8;
typedef __attribute__((ext_vector_type(4)))  unsigned short u16x4;

__device__ __forceinline__ unsigned short f2bf(float f) {
  unsigned u = __float_as_uint(f);
  u += 0x7FFFu + ((u >> 16) & 1u);   // RNE
  return (unsigned short)(u >> 16);
}
__device__ __forceinline__ float bf2f(unsigned short s) {
  return __uint_as_float((unsigned)s << 16);
}

// OCP e4m3fn encode, RNE, clamp to +-448
__device__ __forceinline__ unsigned char f2e4m3(float f) {
  unsigned u = __float_as_uint(f);
  unsigned s = (u >> 24) & 0x80u;
  float a = fabsf(f);
  if (a >= 448.f) return (unsigned char)(s | 0x7E);
  if (a < 0.0009765625f) return (unsigned char)s;          // < 2^-10 -> 0
  int e = (int)((u >> 23) & 0xFF) - 127;
  if (e < -6) {                                            // subnormal, q = 2^-9
    int q = (int)rintf(a * 512.f);
    if (q >= 8) return (unsigned char)(s | 0x08);
    return (unsigned char)(s | q);
  }
  unsigned mant = u & 0x7FFFFFu;
  unsigned mr = mant + 0x7FFFFu + ((mant >> 20) & 1u);     // RNE at bit 20
  e += (int)(mr >> 23);
  mant = (mr >> 20) & 7u;
  if (e > 8) return (unsigned char)(s | 0x7E);
  return (unsigned char)(s | ((e + 7) << 3) | mant);
}

__device__ __forceinline__ float e4m3f(unsigned v) {
  unsigned e = (v >> 3) & 15u, m = v & 7u;
  float mag = (e == 0) ? (float)m * 0.001953125f
                       : __uint_as_float(((e + 120u) << 23) | (m << 20));
  return (v & 0x80u) ? -mag : mag;
}
__device__ __forceinline__ void dec8(uint2 p, float* o) {
#pragma unroll
  for (int j = 0; j < 4; ++j) o[j]     = e4m3f((p.x >> (8 * j)) & 255u);
#pragma unroll
  for (int j = 0; j < 4; ++j) o[4 + j] = e4m3f((p.y >> (8 * j)) & 255u);
}

__device__ __forceinline__ void async16(const void* g, void* l) {
  __builtin_amdgcn_global_load_lds((__attribute__((address_space(1))) void*)g,
                                   (__attribute__((address_space(3))) void*)l,
                                   16, 0, 0);
}

// ---------------------------------------------------------------------------
// bf16 256x256 GEMM (r4 structure, unchanged). MODE 0: bf16 out; MODE 2: +res f32.
// ---------------------------------------------------------------------------
template<int MODE>
__global__ __launch_bounds__(512, 2)
void gemm256(const unsigned short* __restrict__ A,
             const unsigned short* __restrict__ Bt,
             const float* __restrict__ bias,
             void* __restrict__ Cout,
             const unsigned short* __restrict__ res,
             int Kdim, int Ndim, int NN)
{
  __shared__ __align__(16) char lds[131072];
  const int tid  = threadIdx.x;
  const int lane = tid & 63, w = tid >> 6;
  const int wm = w >> 2, wn = w & 3;
  const int li = lane & 15, lc = lane >> 4;

  const int nwg = gridDim.x;
  const int q8 = nwg >> 3, r8 = nwg & 7;
  const int xcd = blockIdx.x & 7, pos = blockIdx.x >> 3;
  const int swz = (xcd < r8 ? xcd * (q8 + 1) : r8 * (q8 + 1) + (xcd - r8) * q8) + pos;
  const int bm = (swz / NN) * 256;
  const int bn = (swz % NN) * 256;

  const int r0  = w * 32 + (lane >> 2);
  const int csw = ((lane & 3) ^ ((r0 >> 1) & 3)) * 8;
  const size_t aS0 = (size_t)(bm + r0) * Kdim + csw;
  const size_t aS1 = (size_t)(bm + r0 + 16) * Kdim + csw;
  const size_t bS0 = (size_t)(bn + r0) * Kdim + csw;
  const size_t bS1 = (size_t)(bn + r0 + 16) * Kdim + csw;
  const int dL0 = w * 2048, dL1 = dL0 + 1024;

  const int fsw   = (lc ^ ((li >> 1) & 3)) << 4;
  const int afoff = (wm * 128 + li) * 64 + fsw;
  const int bfoff = 32768 + (wn * 64 + li) * 64 + fsw;

  f32x4 acc[8][4];
#pragma unroll
  for (int m = 0; m < 8; ++m)
#pragma unroll
    for (int n = 0; n < 4; ++n) acc[m][n] = (f32x4)0.f;

  const int NT = Kdim >> 6;

  async16(A  + aS0,       lds + dL0);          async16(A  + aS1,       lds + dL1);
  async16(Bt + bS0,       lds + 32768 + dL0);  async16(Bt + bS1,       lds + 32768 + dL1);
  async16(A  + aS0 + 32,  lds + 16384 + dL0);  async16(A  + aS1 + 32,  lds + 16384 + dL1);
  async16(Bt + bS0 + 32,  lds + 49152 + dL0);  async16(Bt + bS1 + 32,  lds + 49152 + dL1);
  async16(A  + aS0 + 64,  lds + 65536 + dL0);  async16(A  + aS1 + 64,  lds + 65536 + dL1);
  async16(Bt + bS0 + 64,  lds + 98304 + dL0);  async16(Bt + bS1 + 64,  lds + 98304 + dL1);
  asm volatile("s_waitcnt vmcnt(4)" ::: "memory");
  __builtin_amdgcn_s_barrier();

  for (int t = 0; t < NT; ++t) {
    char* buf  = lds + (t & 1) * 65536;
    char* nbuf = lds + ((t + 1) & 1) * 65536;
    const size_t kA = (size_t)t * 64;
    const bool s1 = (t + 1 < NT), s2 = (t + 2 < NT);
    s16x8 aR[4], bR[4];

    { // ph0
      const char* ab = buf + afoff;
      const char* bb = buf + bfoff;
#pragma unroll
      for (int i = 0; i < 4; ++i) aR[i] = *(const s16x8*)(ab + i * 1024);
#pragma unroll
      for (int i = 0; i < 4; ++i) bR[i] = *(const s16x8*)(bb + i * 1024);
      if (s1) {
        async16(A + aS0 + kA + 96, nbuf + 16384 + dL0);
        async16(A + aS1 + kA + 96, nbuf + 16384 + dL1);
      }
      __builtin_amdgcn_s_setprio(1);
#pragma unroll
      for (int mf = 0; mf < 4; ++mf)
#pragma unroll
        for (int nf = 0; nf < 4; ++nf)
          acc[mf][nf] = __builtin_amdgcn_mfma_f32_16x16x32_bf16(aR[mf], bR[nf], acc[mf][nf], 0, 0, 0);
      __builtin_amdgcn_s_setprio(0);
      __builtin_amdgcn_s_barrier();
    }
    { // ph1
      const char* ab = buf + afoff + 4096;
#pragma unroll
      for (int i = 0; i < 4; ++i) aR[i] = *(const s16x8*)(ab + i * 1024);
      if (s1) {
        async16(Bt + bS0 + kA + 96, nbuf + 49152 + dL0);
        async16(Bt + bS1 + kA + 96, nbuf + 49152 + dL1);
      }
      __builtin_amdgcn_s_setprio(1);
#pragma unroll
      for (int mf = 0; mf < 4; ++mf)
#pragma unroll
        for (int nf = 0; nf < 4; ++nf)
          acc[4 + mf][nf] = __builtin_amdgcn_mfma_f32_16x16x32_bf16(aR[mf], bR[nf], acc[4 + mf][nf], 0, 0, 0);
      __builtin_amdgcn_s_setprio(0);
      __builtin_amdgcn_s_barrier();
    }
    { // ph2
      const char* ab = buf + 16384 + afoff;
      const char* bb = buf + 16384 + bfoff;
#pragma unroll
      for (int i = 0; i < 4; ++i) aR[i] = *(const s16x8*)(ab + i * 1024);
#pragma unroll
      for (int i = 0; i < 4; ++i) bR[i] = *(const s16x8*)(bb + i * 1024);
      if (s2) {
        async16(A + aS0 + kA + 128, buf + dL0);
        async16(A + aS1 + kA + 128, buf + dL1);
      }
      __builtin_amdgcn_s_setprio(1);
#pragma unroll
      for (int mf = 0; mf < 4; ++mf)
#pragma unroll
        for (int nf = 0; nf < 4; ++nf)
          acc[mf][nf] = __builtin_amdgcn_mfma_f32_16x16x32_bf16(aR[mf], bR[nf], acc[mf][nf], 0, 0, 0);
      __builtin_amdgcn_s_setprio(0);
      __builtin_amdgcn_s_barrier();
    }
    { // ph3
      const char* ab = buf + 16384 + afoff + 4096;
#pragma unroll
      for (int i = 0; i < 4; ++i) aR[i] = *(const s16x8*)(ab + i * 1024);
      if (s2) {
        async16(Bt + bS0 + kA + 128, buf + 32768 + dL0);
        async16(Bt + bS1 + kA + 128, buf + 32768 + dL1);
      }
      __builtin_amdgcn_s_setprio(1);
#pragma unroll
      for (int mf = 0; mf < 4; ++mf)
#pragma unroll
        for (int nf = 0; nf < 4; ++nf)
          acc[4 + mf][nf] = __builtin_amdgcn_mfma_f32_16x16x32_bf16(aR[mf], bR[nf], acc[4 + mf][nf], 0, 0, 0);
      __builtin_amdgcn_s_setprio(0);
      if (t < NT - 2)       { asm volatile("s_waitcnt vmcnt(4)" ::: "memory"); }
      else if (t == NT - 2) { asm volatile("s_waitcnt vmcnt(0)" ::: "memory"); }
      __builtin_amdgcn_s_barrier();
    }
  }

  float bv[4];
#pragma unroll
  for (int n = 0; n < 4; ++n) bv[n] = bias[bn + wn * 64 + n * 16 + li];

  if (MODE == 0) {
    unsigned short* Cb = (unsigned short*)Cout;
    unsigned short* wl0 = (unsigned short*)(lds + w * 12288);
#pragma unroll
    for (int mp = 0; mp < 4; ++mp) {
      unsigned short* wl = wl0 + (mp & 1) * 2304;
#pragma unroll
      for (int mi = 0; mi < 2; ++mi)
#pragma unroll
        for (int n = 0; n < 4; ++n)
#pragma unroll
          for (int jj = 0; jj < 4; ++jj) {
            float v = acc[mp * 2 + mi][n][jj] + bv[n];
            wl[(mi * 16 + lc * 4 + jj) * 72 + li + n * 16] = f2bf(v);
          }
#pragma unroll
      for (int i = 0; i < 4; ++i) {
        const int rr = i * 8 + (lane >> 3);
        u16x8 vv = *(const u16x8*)(wl + rr * 72 + (lane & 7) * 8);
        const size_t gi = (size_t)(bm + wm * 128 + mp * 32 + rr) * Ndim
                        + bn + wn * 64 + (lane & 7) * 8;
        *(u16x8*)(Cb + gi) = vv;
      }
    }
  } else {
    float* Cf = (float*)Cout;
    float* wl0 = (float*)(lds + w * 12288);
#pragma unroll
    for (int m = 0; m < 8; ++m) {
      float* wl = wl0 + (m & 1) * 1088;
#pragma unroll
      for (int n = 0; n < 4; ++n)
#pragma unroll
        for (int jj = 0; jj < 4; ++jj)
          wl[(lc * 4 + jj) * 68 + li + n * 16] = acc[m][n][jj] + bv[n];
#pragma unroll
      for (int i = 0; i < 4; ++i) {
        const int rr = i * 4 + lc;
        f32x4 vv = *(const f32x4*)(wl + rr * 68 + li * 4);
        const size_t gi = (size_t)(bm + wm * 128 + m * 16 + rr) * Ndim
                        + bn + wn * 64 + li * 4;
        const u16x4 rv = *(const u16x4*)(res + gi);
        f32x4 ov;
#pragma unroll
        for (int jj = 0; jj < 4; ++jj) ov[jj] = vv[jj] + bf2f(rv[jj]);
        *(f32x4*)(Cf + gi) = ov;
      }
    }
  }
}

// ---------------------------------------------------------------------------
// fp8 256x256 GEMM: C[M,4096](fp8) = A[M,1024](fp8) @ Bt[4096,1024]^T(fp8) + bias
// Same structure as gemm256: K-tile = 128 fp8 (two 64B halves), 16KB regions,
// identical stage/vmcnt ledger. Fragments are 8B (ds_read_b64), MFMA
// 16x16x32_fp8_fp8. 32 MFMA per phase.
// ---------------------------------------------------------------------------
__global__ __launch_bounds__(512, 2)
void gemm_fp8(const unsigned char* __restrict__ A,
              const unsigned char* __restrict__ Bt,
              const float* __restrict__ bias,
              unsigned char* __restrict__ Cout,
              int Kb, int Ndim, int NN)
{
  __shared__ __align__(16) char lds[131072];
  const int tid  = threadIdx.x;
  const int lane = tid & 63, w = tid >> 6;
  const int wm = w >> 2, wn = w & 3;
  const int li = lane & 15, lc = lane >> 4;

  const int nwg = gridDim.x;
  const int q8 = nwg >> 3, r8 = nwg & 7;
  const int xcd = blockIdx.x & 7, pos = blockIdx.x >> 3;
  const int swz = (xcd < r8 ? xcd * (q8 + 1) : r8 * (q8 + 1) + (xcd - r8) * q8) + pos;
  const int bm = (swz / NN) * 256;
  const int bn = (swz % NN) * 256;

  // staging: region [256 rows][64 B]; thread 2x16B (rows r0, r0+16)
  const int r0  = w * 32 + (lane >> 2);
  const int csw = ((lane & 3) ^ ((r0 >> 1) & 3)) * 16;   // bytes
  const size_t aS0 = (size_t)(bm + r0) * Kb + csw;
  const size_t aS1 = (size_t)(bm + r0 + 16) * Kb + csw;
  const size_t bS0 = (size_t)(bn + r0) * Kb + csw;
  const size_t bS1 = (size_t)(bn + r0 + 16) * Kb + csw;
  const int dL0 = w * 2048, dL1 = dL0 + 1024;

  // fragment byte offsets: logical 16B chunk cL = ks*2 + (lc>>1), half = lc&1
  const int xorv  = (li >> 1) & 3;
  const int o_ks0 = ((((lc >> 1) + 0)) ^ xorv) * 16 + (lc & 1) * 8;
  const int o_ks1 = ((((lc >> 1) + 2)) ^ xorv) * 16 + (lc & 1) * 8;
  const int aBase = (wm * 128 + li) * 64;
  const int bBase = 32768 + (wn * 64 + li) * 64;

  f32x4 acc[8][4];
#pragma unroll
  for (int m = 0; m < 8; ++m)
#pragma unroll
    for (int n = 0; n < 4; ++n) acc[m][n] = (f32x4)0.f;

  const int NT = Kb >> 7;   // 8

  // prologue: K0(0), K1(0), K0(1); vmcnt(4) leaves K0(1)
  async16(A  + aS0,        lds + dL0);          async16(A  + aS1,        lds + dL1);
  async16(Bt + bS0,        lds + 32768 + dL0);  async16(Bt + bS1,        lds + 32768 + dL1);
  async16(A  + aS0 + 64,   lds + 16384 + dL0);  async16(A  + aS1 + 64,   lds + 16384 + dL1);
  async16(Bt + bS0 + 64,   lds + 49152 + dL0);  async16(Bt + bS1 + 64,   lds + 49152 + dL1);
  async16(A  + aS0 + 128,  lds + 65536 + dL0);  async16(A  + aS1 + 128,  lds + 65536 + dL1);
  async16(Bt + bS0 + 128,  lds + 98304 + dL0);  async16(Bt + bS1 + 128,  lds + 98304 + dL1);
  asm volatile("s_waitcnt vmcnt(4)" ::: "memory");
  __builtin_amdgcn_s_barrier();

  for (int t = 0; t < NT; ++t) {
    char* buf  = lds + (t & 1) * 65536;
    char* nbuf = lds + ((t + 1) & 1) * 65536;
    const size_t kA = (size_t)t * 128;
    const bool s1 = (t + 1 < NT), s2 = (t + 2 < NT);
    long aF[4][2], bF[4][2];

    { // ph0: half0 m0-3 + B; stage AK1(t+1)
      const char* ar = buf + aBase;
      const char* br = buf + bBase;
#pragma unroll
      for (int i = 0; i < 4; ++i) {
        aF[i][0] = *(const long*)(ar + i * 1024 + o_ks0);
        aF[i][1] = *(const long*)(ar + i * 1024 + o_ks1);
        bF[i][0] = *(const long*)(br + i * 1024 + o_ks0);
        bF[i][1] = *(const long*)(br + i * 1024 + o_ks1);
      }
      if (s1) {
        async16(A + aS0 + kA + 192, nbuf + 16384 + dL0);
        async16(A + aS1 + kA + 192, nbuf + 16384 + dL1);
      }
      __builtin_amdgcn_s_setprio(1);
#pragma unroll
      for (int mf = 0; mf < 4; ++mf)
#pragma unroll
        for (int nf = 0; nf < 4; ++nf) {
          acc[mf][nf] = __builtin_amdgcn_mfma_f32_16x16x32_fp8_fp8(aF[mf][0], bF[nf][0], acc[mf][nf], 0, 0, 0);
          acc[mf][nf] = __builtin_amdgcn_mfma_f32_16x16x32_fp8_fp8(aF[mf][1], bF[nf][1], acc[mf][nf], 0, 0, 0);
        }
      __builtin_amdgcn_s_setprio(0);
      __builtin_amdgcn_s_barrier();
    }
    { // ph1: half0 m4-7 (reuse bF); stage BK1(t+1)
      const char* ar = buf + aBase + 4096;
#pragma unroll
      for (int i = 0; i < 4; ++i) {
        aF[i][0] = *(const long*)(ar + i * 1024 + o_ks0);
        aF[i][1] = *(const long*)(ar + i * 1024 + o_ks1);
      }
      if (s1) {
        async16(Bt + bS0 + kA + 192, nbuf + 49152 + dL0);
        async16(Bt + bS1 + kA + 192, nbuf + 49152 + dL1);
      }
      __builtin_amdgcn_s_setprio(1);
#pragma unroll
      for (int mf = 0; mf < 4; ++mf)
#pragma unroll
        for (int nf = 0; nf < 4; ++nf) {
          acc[4 + mf][nf] = __builtin_amdgcn_mfma_f32_16x16x32_fp8_fp8(aF[mf][0], bF[nf][0], acc[4 + mf][nf], 0, 0, 0);
          acc[4 + mf][nf] = __builtin_amdgcn_mfma_f32_16x16x32_fp8_fp8(aF[mf][1], bF[nf][1], acc[4 + mf][nf], 0, 0, 0);
        }
      __builtin_amdgcn_s_setprio(0);
      __builtin_amdgcn_s_barrier();
    }
    { // ph2: half1 m0-3 + B; stage AK0(t+2)
      const char* ar = buf + 16384 + aBase;
      const char* br = buf + 16384 + bBase;
#pragma unroll
      for (int i = 0; i < 4; ++i) {
        aF[i][0] = *(const long*)(ar + i * 1024 + o_ks0);
        aF[i][1] = *(const long*)(ar + i * 1024 + o_ks1);
        bF[i][0] = *(const long*)(br + i * 1024 + o_ks0);
        bF[i][1] = *(const long*)(br + i * 1024 + o_ks1);
      }
      if (s2) {
        async16(A + aS0 + kA + 256, buf + dL0);
        async16(A + aS1 + kA + 256, buf + dL1);
      }
      __builtin_amdgcn_s_setprio(1);
#pragma unroll
      for (int mf = 0; mf < 4; ++mf)
#pragma unroll
        for (int nf = 0; nf < 4; ++nf) {
          acc[mf][nf] = __builtin_amdgcn_mfma_f32_16x16x32_fp8_fp8(aF[mf][0], bF[nf][0], acc[mf][nf], 0, 0, 0);
          acc[mf][nf] = __builtin_amdgcn_mfma_f32_16x16x32_fp8_fp8(aF[mf][1], bF[nf][1], acc[mf][nf], 0, 0, 0);
        }
      __builtin_amdgcn_s_setprio(0);
      __builtin_amdgcn_s_barrier();
    }
    { // ph3: half1 m4-7; stage BK0(t+2); counted wait
      const char* ar = buf + 16384 + aBase + 4096;
#pragma unroll
      for (int i = 0; i < 4; ++i) {
        aF[i][0] = *(const long*)(ar + i * 1024 + o_ks0);
        aF[i][1] = *(const long*)(ar + i * 1024 + o_ks1);
      }
      if (s2) {
        async16(Bt + bS0 + kA + 256, buf + 32768 + dL0);
        async16(Bt + bS1 + kA + 256, buf + 32768 + dL1);
      }
      __builtin_amdgcn_s_setprio(1);
#pragma unroll
      for (int mf = 0; mf < 4; ++mf)
#pragma unroll
        for (int nf = 0; nf < 4; ++nf) {
          acc[4 + mf][nf] = __builtin_amdgcn_mfma_f32_16x16x32_fp8_fp8(aF[mf][0], bF[nf][0], acc[4 + mf][nf], 0, 0, 0);
          acc[4 + mf][nf] = __builtin_amdgcn_mfma_f32_16x16x32_fp8_fp8(aF[mf][1], bF[nf][1], acc[4 + mf][nf], 0, 0, 0);
        }
      __builtin_amdgcn_s_setprio(0);
      if (t < NT - 2)       { asm volatile("s_waitcnt vmcnt(4)" ::: "memory"); }
      else if (t == NT - 2) { asm volatile("s_waitcnt vmcnt(0)" ::: "memory"); }
      __builtin_amdgcn_s_barrier();
    }
  }

  // epilogue: fp8 store via per-wave LDS shuffle
  float bv[4];
#pragma unroll
  for (int n = 0; n < 4; ++n) bv[n] = bias[bn + wn * 64 + n * 16 + li];

  unsigned char* wl0 = (unsigned char*)(lds + w * 12288);
#pragma unroll
  for (int mp = 0; mp < 4; ++mp) {
    unsigned char* wl = wl0 + (mp & 1) * 2304;
#pragma unroll
    for (int mi = 0; mi < 2; ++mi)
#pragma unroll
      for (int n = 0; n < 4; ++n)
#pragma unroll
        for (int jj = 0; jj < 4; ++jj) {
          float v = acc[mp * 2 + mi][n][jj] + bv[n];
          wl[(mi * 16 + lc * 4 + jj) * 72 + n * 16 + li] = f2e4m3(v);
        }
#pragma unroll
    for (int i = 0; i < 4; ++i) {
      const int rr = i * 8 + (lane >> 3);
      uint2 vv = *(const uint2*)(wl + rr * 72 + (lane & 7) * 8);
      const size_t gi = (size_t)(bm + wm * 128 + mp * 32 + rr) * Ndim
                      + bn + wn * 64 + (lane & 7) * 8;
      *(uint2*)(Cout + gi) = vv;
    }
  }
}

// ---------------------------------------------------------------------------
// 128x128 GEMM — lambda-net hidden GEMM only.
// ---------------------------------------------------------------------------
__global__ __launch_bounds__(256, 2)
void gemm_bf16_relu(const unsigned short* __restrict__ A,
                    const unsigned short* __restrict__ Bt,
                    const float* __restrict__ bias,
                    unsigned short* __restrict__ Cout,
                    int Kdim, int Ndim)
{
  __shared__ __align__(16) unsigned short lA[128 * 32];
  __shared__ __align__(16) unsigned short lB[128 * 32];
  const int tid  = threadIdx.x;
  const int lane = tid & 63, wid = tid >> 6;
  const int wm = wid >> 1, wn = wid & 1;
  const int bm = blockIdx.x * 128, bn = blockIdx.y * 128;

  f32x4 acc[4][4];
#pragma unroll
  for (int i = 0; i < 4; ++i)
#pragma unroll
    for (int j = 0; j < 4; ++j) acc[i][j] = (f32x4)0.f;

  const int ar = tid >> 2;
  const int ac = (tid & 3) * 8;
  const unsigned short* aG0 = A  + (size_t)(bm + ar) * Kdim + ac;
  const unsigned short* aG1 = aG0 + (size_t)64 * Kdim;
  const unsigned short* bG0 = Bt + (size_t)(bn + ar) * Kdim + ac;
  const unsigned short* bG1 = bG0 + (size_t)64 * Kdim;
  unsigned short* aL0 = lA + wid * 512;
  unsigned short* aL1 = lA + 2048 + wid * 512;
  unsigned short* bL0 = lB + wid * 512;
  unsigned short* bL1 = lB + 2048 + wid * 512;

  const unsigned short* aF = lA + (wm * 64 + (lane & 15)) * 32 + (lane >> 4) * 8;
  const unsigned short* bF = lB + (wn * 64 + (lane & 15)) * 32 + (lane >> 4) * 8;

  for (int k0 = 0; k0 < Kdim; k0 += 32) {
    async16(aG0, aL0); async16(aG1, aL1);
    async16(bG0, bL0); async16(bG1, bL1);
    aG0 += 32; aG1 += 32; bG0 += 32; bG1 += 32;
    __syncthreads();
    s16x8 af[4], bw[4];
#pragma unroll
    for (int m = 0; m < 4; ++m) af[m] = *(const s16x8*)(aF + m * 512);
#pragma unroll
    for (int n = 0; n < 4; ++n) bw[n] = *(const s16x8*)(bF + n * 512);
#pragma unroll
    for (int m = 0; m < 4; ++m)
#pragma unroll
      for (int n = 0; n < 4; ++n)
        acc[m][n] = __builtin_amdgcn_mfma_f32_16x16x32_bf16(af[m], bw[n], acc[m][n], 0, 0, 0);
    __syncthreads();
  }

  const int r0 = bm + wm * 64 + ((lane >> 4) << 2);
  const int c0 = bn + wn * 64 + (lane & 15);
#pragma unroll
  for (int m = 0; m < 4; ++m)
#pragma unroll
    for (int n = 0; n < 4; ++n) {
      const int col = c0 + n * 16;
      const float bvv = bias[col];
#pragma unroll
      for (int j = 0; j < 4; ++j) {
        const int row = r0 + m * 16 + j;
        Cout[(size_t)row * Ndim + col] = f2bf(fmaxf(acc[m][n][j] + bvv, 0.f));
      }
    }
}

// ---------------------------------------------------------------------------
// lam[row] = sigmoid( relu_h[row,:] . L2w + L2b )
// ---------------------------------------------------------------------------
__global__ void lam_kernel(const unsigned short* __restrict__ h,
                           const float* __restrict__ L2w,
                           const float* __restrict__ L2b,
                           float* __restrict__ lam)
{
  const int lane = threadIdx.x & 63, wid = threadIdx.x >> 6;
  const int row = blockIdx.x * 4 + wid;
  const u16x4 hv = *(const u16x4*)(h + (size_t)row * 256 + lane * 4);
  const float4 wv = ((const float4*)L2w)[lane];
  float s = bf2f(hv[0]) * wv.x + bf2f(hv[1]) * wv.y +
            bf2f(hv[2]) * wv.z + bf2f(hv[3]) * wv.w;
#pragma unroll
  for (int m = 32; m >= 1; m >>= 1) s += __shfl_xor(s, m, 64);
  if (lane == 0) lam[row] = 1.f / (1.f + expf(-(s + L2b[0])));
}

// ---------------------------------------------------------------------------
// Attention core. qk8 [32768,4096] fp8 (Q1|K1|Q2|K2), vbuf [32768,1024] bf16.
// ---------------------------------------------------------------------------
__global__ __launch_bounds__(256)
void attn_kernel(const unsigned char* __restrict__ qk8,
                 const unsigned short* __restrict__ vbuf,
                 const float* __restrict__ lam,
                 unsigned short* __restrict__ aout)
{
  const int b = blockIdx.x;
  const int hd = threadIdx.x >> 6;
  const int lane = threadIdx.x & 63;
  const int g = lane >> 5;
  const int l5 = lane & 31;
  const size_t row = (size_t)(2 * b + g);
  const size_t b8 = row * 4096 + hd * 256 + l5 * 8;

  const uint2 p1 = *(const uint2*)(qk8 + b8);
  const uint2 p2 = *(const uint2*)(qk8 + b8 + 1024);
  const uint2 p3 = *(const uint2*)(qk8 + b8 + 2048);
  const uint2 p4 = *(const uint2*)(qk8 + b8 + 3072);
  const u16x8 vvv = *(const u16x8*)(vbuf + row * 1024 + hd * 256 + l5 * 8);

  float q1[8], k1[8], q2[8], k2[8], vf[8];
  dec8(p1, q1); dec8(p2, k1); dec8(p3, q2); dec8(p4, k2);
#pragma unroll
  for (int j = 0; j < 8; ++j) vf[j] = bf2f(vvv[j]);

  float ss1 = 0.f, sc1 = 0.f, ss2 = 0.f, sc2 = 0.f;
#pragma unroll
  for (int j = 0; j < 8; ++j) {
    const float k1o = __shfl_xor(k1[j], 32, 64);
    const float k2o = __shfl_xor(k2[j], 32, 64);
    ss1 += q1[j] * k1[j]; sc1 += q1[j] * k1o;
    ss2 += q2[j] * k2[j]; sc2 += q2[j] * k2o;
  }
#pragma unroll
  for (int m = 16; m >= 1; m >>= 1) {
    ss1 += __shfl_xor(ss1, m, 64); sc1 += __shfl_xor(sc1, m, 64);
    ss2 += __shfl_xor(ss2, m, 64); sc2 += __shfl_xor(sc2, m, 64);
  }

  float e0 = ss1 * ATT_SCALE, e1 = sc1 * ATT_SCALE;
  float mx = fmaxf(e0, e1);
  float xs = expf(e0 - mx), xc = expf(e1 - mx);
  float inv = 1.f / (xs + xc);
  const float a1s = xs * inv, a1c = xc * inv;

  e0 = ss2 * ATT_SCALE; e1 = sc2 * ATT_SCALE;
  mx = fmaxf(e0, e1);
  xs = expf(e0 - mx); xc = expf(e1 - mx);
  inv = 1.f / (xs + xc);
  const float a2s = xs * inv, a2c = xc * inv;

  const float lm = lam[b];
  const float ps = fmaxf(a1s - lm * a2s, 0.f);
  const float pc = fmaxf(a1c - lm * a2c, 0.f);

  u16x8 o;
#pragma unroll
  for (int j = 0; j < 8; ++j) {
    const float vo = __shfl_xor(vf[j], 32, 64);
    o[j] = f2bf(ps * vf[j] + pc * vo);
  }
  *(u16x8*)(aout + row * 1024 + hd * 256 + l5 * 8) = o;
}

// ---------------------------------------------------------------------------
// conversions
// ---------------------------------------------------------------------------
// x f32 -> x_bf (bf16) + x_f8 (e4m3), one pass
__global__ void conv_x_k(const float* __restrict__ in,
                         unsigned short* __restrict__ xb,
                         unsigned char* __restrict__ x8, int n8)
{
  const int i = blockIdx.x * 256 + threadIdx.x;
  if (i >= n8) return;
  const float4* p = (const float4*)in + (size_t)i * 2;
  float4 a = p[0], b = p[1];
  float f[8] = {a.x, a.y, a.z, a.w, b.x, b.y, b.z, b.w};
  u16x8 v; uint2 c;
  unsigned lo = 0, hi = 0;
#pragma unroll
  for (int j = 0; j < 8; ++j) v[j] = f2bf(f[j]);
#pragma unroll
  for (int j = 0; j < 4; ++j) lo |= (unsigned)f2e4m3(f[j]) << (8 * j);
#pragma unroll
  for (int j = 0; j < 4; ++j) hi |= (unsigned)f2e4m3(f[4 + j]) << (8 * j);
  c.x = lo; c.y = hi;
  *(u16x8*)(xb + (size_t)i * 8) = v;
  *(uint2*)(x8 + (size_t)i * 8) = c;
}

// 6x batched weight transpose: z=0..3 -> fp8 (Q1,K1,Q2,K2), z=4 -> V bf16, z=5 -> WO bf16
__global__ void transpose6_k(const float* __restrict__ s0, const float* __restrict__ s1,
                             const float* __restrict__ s2, const float* __restrict__ s3,
                             const float* __restrict__ s4, const float* __restrict__ s5,
                             unsigned char* __restrict__ qw8,
                             unsigned short* __restrict__ vw,
                             unsigned short* __restrict__ wot)
{
  __shared__ float tile[32][33];
  const int z = blockIdx.z;
  const float* W;
  switch (z) {
    case 0: W = s0; break;
    case 1: W = s1; break;
    case 2: W = s2; break;
    case 3: W = s3; break;
    case 4: W = s4; break;
    default: W = s5; break;
  }
  const int bn = blockIdx.x * 32, bk = blockIdx.y * 32;
  const int tx = threadIdx.x, ty = threadIdx.y;
#pragma unroll
  for (int i = ty; i < 32; i += 8)
    tile[i][tx] = W[(size_t)(bk + i) * 1024 + bn + tx];
  __syncthreads();
  if (z < 4) {
    unsigned char* Wt = qw8 + (size_t)z * 1048576;
#pragma unroll
    for (int i = ty; i < 32; i += 8)
      Wt[(size_t)(bn + i) * 1024 + bk + tx] = f2e4m3(tile[tx][i]);
  } else {
    unsigned short* Wt = (z == 4) ? vw : wot;
#pragma unroll
    for (int i = ty; i < 32; i += 8)
      Wt[(size_t)(bn + i) * 1024 + bk + tx] = f2bf(tile[tx][i]);
  }
}

// W f32 [K,N] -> Wt bf16 [N,K]
__global__ void transpose_bf16_k(const float* __restrict__ W,
                                 unsigned short* __restrict__ Wt, int K, int N)
{
  __shared__ float tile[32][33];
  const int bn = blockIdx.x * 32, bk = blockIdx.y * 32;
  const int tx = threadIdx.x, ty = threadIdx.y;
#pragma unroll
  for (int i = ty; i < 32; i += 8)
    tile[i][tx] = W[(size_t)(bk + i) * N + bn + tx];
  __syncthreads();
#pragma unroll
  for (int i = ty; i < 32; i += 8)
    Wt[(size_t)(bn + i) * K + bk + tx] = f2bf(tile[tx][i]);
}

__global__ void concat_bias4(const float* __restrict__ b0, const float* __restrict__ b1,
                             const float* __restrict__ b2, const float* __restrict__ b3,
                             float* __restrict__ out)
{
  const int i = blockIdx.x * 256 + threadIdx.x;   // 4096 total
  const float* src;
  switch (i >> 10) {
    case 0: src = b0; break;
    case 1: src = b1; break;
    case 2: src = b2; break;
    default: src = b3; break;
  }
  out[i] = src[i & 1023];
}

// ---------------------------------------------------------------------------
extern "C" void kernel_launch(void* const* d_in, const int* in_sizes, int n_in,
                              void* d_out, int out_size, void* d_ws, size_t ws_size,
                              hipStream_t stream)
{
  const float* x    = (const float*)d_in[0];
  const float* WQ1w = (const float*)d_in[1];  const float* WQ1b = (const float*)d_in[2];
  const float* WK1w = (const float*)d_in[3];  const float* WK1b = (const float*)d_in[4];
  const float* WQ2w = (const float*)d_in[5];  const float* WQ2b = (const float*)d_in[6];
  const float* WK2w = (const float*)d_in[7];  const float* WK2b = (const float*)d_in[8];
  const float* WVw  = (const float*)d_in[9];  const float* WVb  = (const float*)d_in[10];
  const float* WOw  = (const float*)d_in[11]; const float* WOb  = (const float*)d_in[12];
  const float* L1w  = (const float*)d_in[13]; const float* L1b  = (const float*)d_in[14];
  const float* L2w  = (const float*)d_in[15]; const float* L2b  = (const float*)d_in[16];

  char* ws = (char*)d_ws;
  size_t off = 0;
  unsigned short* x_bf = (unsigned short*)(ws + off); off += (size_t)33554432 * 2;   // 64MB
  unsigned char*  x_f8 = (unsigned char*)(ws + off);  off += (size_t)33554432;       // 32MB
  unsigned char*  qw8  = (unsigned char*)(ws + off);  off += (size_t)4194304;        // 4MB [4096,1024]
  unsigned short* vw   = (unsigned short*)(ws + off); off += (size_t)1048576 * 2;    // 2MB
  unsigned short* wot  = (unsigned short*)(ws + off); off += (size_t)1048576 * 2;    // 2MB
  unsigned short* l1t  = (unsigned short*)(ws + off); off += (size_t)524288 * 2;     // 1MB
  float*          bcat = (float*)(ws + off);          off += (size_t)4096 * 4;
  unsigned char*  qk8  = (unsigned char*)(ws + off);  off += (size_t)32768 * 4096;   // 128MB
  unsigned short* vbuf = (unsigned short*)(ws + off); off += (size_t)33554432 * 2;   // 64MB
  unsigned short* abuf = (unsigned short*)(ws + off); off += (size_t)33554432 * 2;   // 64MB
  unsigned short* hbuf = (unsigned short*)(ws + off); off += (size_t)16384 * 256 * 2;
  float*          lam  = (float*)(ws + off);          off += (size_t)16384 * 4;

  // conversions
  conv_x_k<<<4194304 / 256, 256, 0, stream>>>(x, x_bf, x_f8, 4194304);
  dim3 tb(32, 8);
  transpose6_k<<<dim3(32, 32, 6), tb, 0, stream>>>(WQ1w, WK1w, WQ2w, WK2w, WVw, WOw, qw8, vw, wot);
  transpose_bf16_k<<<dim3(8, 64), tb, 0, stream>>>(L1w, l1t, 2048, 256);
  concat_bias4<<<16, 256, 0, stream>>>(WQ1b, WK1b, WQ2b, WK2b, bcat);

  // lambda net
  gemm_bf16_relu<<<dim3(128, 2), 256, 0, stream>>>(x_bf, l1t, L1b, hbuf, 2048, 256);
  lam_kernel<<<4096, 256, 0, stream>>>(hbuf, L2w, L2b, lam);

  // fp8 projections: [32768,1024] @ [1024,4096] -> qk8 (Q1|K1|Q2|K2)
  gemm_fp8<<<dim3(128 * 16), 512, 0, stream>>>(x_f8, qw8, bcat, qk8, 1024, 4096, 16);

  // V projection (bf16): [32768,1024] @ [1024,1024] -> vbuf
  gemm256<0><<<dim3(128 * 4), 512, 0, stream>>>(x_bf, vw, WVb, vbuf, nullptr, 1024, 1024, 4);

  // attention core
  attn_kernel<<<16384, 256, 0, stream>>>(qk8, vbuf, lam, abuf);

  // output: attn @ WO + bias + residual(x_bf), f32
  gemm256<2><<<dim3(128 * 4), 512, 0, stream>>>(abuf, wot, WOb, d_out, x_bf, 1024, 1024, 4);
}

// Round 8
// 695.178 us; speedup vs baseline: 1.0127x; 1.0127x over previous
//
#include <hip/hip_runtime.h>
#include <stdint.h>

// ---------------------------------------------------------------------------
// AdaptiveDiffAttention on MI355X (gfx950)
// Round 8: r4's bf16 GEMM (best, 354us) restored. Q1/K1/Q2/K2 stored fp8 from
// the proj epilogue (bf16 compute, e4m3 storage); V bf16. Lambda-net dot fused
// into hidden-GEMM epilogue via atomicAdd; sigmoid applied in attn kernel.
// ---------------------------------------------------------------------------

#define BATCH  16384
#define ATT_SCALE 0.0625f // 256^-0.5

typedef __attribute__((ext_vector_type(8)))  short   s16x8;
typedef __attribute__((ext_vector_type(4)))  float   f32x4;
typedef __attribute__((ext_vector_type(8)))  unsigned short u16x8;
typedef __attribute__((ext_vector_type(4)))  unsigned short u16x4;

__device__ __forceinline__ unsigned short f2bf(float f) {
  unsigned u = __float_as_uint(f);
  u += 0x7FFFu + ((u >> 16) & 1u);   // RNE
  return (unsigned short)(u >> 16);
}
__device__ __forceinline__ float bf2f(unsigned short s) {
  return __uint_as_float((unsigned)s << 16);
}

// OCP e4m3fn encode, RNE, clamp (r7-proven)
__device__ __forceinline__ unsigned char f2e4m3(float f) {
  unsigned u = __float_as_uint(f);
  unsigned s = (u >> 24) & 0x80u;
  float a = fabsf(f);
  if (a >= 448.f) return (unsigned char)(s | 0x7E);
  if (a < 0.0009765625f) return (unsigned char)s;
  int e = (int)((u >> 23) & 0xFF) - 127;
  if (e < -6) {
    int q = (int)rintf(a * 512.f);
    if (q >= 8) return (unsigned char)(s | 0x08);
    return (unsigned char)(s | q);
  }
  unsigned mant = u & 0x7FFFFFu;
  unsigned mr = mant + 0x7FFFFu + ((mant >> 20) & 1u);
  e += (int)(mr >> 23);
  mant = (mr >> 20) & 7u;
  if (e > 8) return (unsigned char)(s | 0x7E);
  return (unsigned char)(s | ((e + 7) << 3) | mant);
}
__device__ __forceinline__ float e4m3f(unsigned v) {
  unsigned e = (v >> 3) & 15u, m = v & 7u;
  float mag = (e == 0) ? (float)m * 0.001953125f
                       : __uint_as_float(((e + 120u) << 23) | (m << 20));
  return (v & 0x80u) ? -mag : mag;
}
__device__ __forceinline__ void dec8(uint2 p, float* o) {
#pragma unroll
  for (int j = 0; j < 4; ++j) o[j]     = e4m3f((p.x >> (8 * j)) & 255u);
#pragma unroll
  for (int j = 0; j < 4; ++j) o[4 + j] = e4m3f((p.y >> (8 * j)) & 255u);
}

__device__ __forceinline__ void async16(const void* g, void* l) {
  __builtin_amdgcn_global_load_lds((__attribute__((address_space(1))) void*)g,
                                   (__attribute__((address_space(3))) void*)l,
                                   16, 0, 0);
}

// ---------------------------------------------------------------------------
// 256x256 GEMM: C = A[M,K](bf16) @ Bt[N,K]^T(bf16) + bias. r4 K-loop verbatim.
// MODE 2: +res(bf16), store f32 to Cout.
// MODE 3: proj split epilogue — cols <4096 -> fp8 to Cout(qk8, stride 4096);
//         cols >=4096 -> bf16 to res-cast(vbuf, stride 1024).
// ---------------------------------------------------------------------------
template<int MODE>
__global__ __launch_bounds__(512, 2)
void gemm256(const unsigned short* __restrict__ A,
             const unsigned short* __restrict__ Bt,
             const float* __restrict__ bias,
             void* __restrict__ Cout,
             const unsigned short* __restrict__ res,
             int Kdim, int Ndim, int NN)
{
  __shared__ __align__(16) char lds[131072];
  const int tid  = threadIdx.x;
  const int lane = tid & 63, w = tid >> 6;
  const int wm = w >> 2, wn = w & 3;
  const int li = lane & 15, lc = lane >> 4;

  const int nwg = gridDim.x;
  const int q8 = nwg >> 3, r8 = nwg & 7;
  const int xcd = blockIdx.x & 7, pos = blockIdx.x >> 3;
  const int swz = (xcd < r8 ? xcd * (q8 + 1) : r8 * (q8 + 1) + (xcd - r8) * q8) + pos;
  const int bm = (swz / NN) * 256;
  const int bn = (swz % NN) * 256;

  const int r0  = w * 32 + (lane >> 2);
  const int csw = ((lane & 3) ^ ((r0 >> 1) & 3)) * 8;
  const size_t aS0 = (size_t)(bm + r0) * Kdim + csw;
  const size_t aS1 = (size_t)(bm + r0 + 16) * Kdim + csw;
  const size_t bS0 = (size_t)(bn + r0) * Kdim + csw;
  const size_t bS1 = (size_t)(bn + r0 + 16) * Kdim + csw;
  const int dL0 = w * 2048, dL1 = dL0 + 1024;

  const int fsw   = (lc ^ ((li >> 1) & 3)) << 4;
  const int afoff = (wm * 128 + li) * 64 + fsw;
  const int bfoff = 32768 + (wn * 64 + li) * 64 + fsw;

  f32x4 acc[8][4];
#pragma unroll
  for (int m = 0; m < 8; ++m)
#pragma unroll
    for (int n = 0; n < 4; ++n) acc[m][n] = (f32x4)0.f;

  const int NT = Kdim >> 6;

  async16(A  + aS0,       lds + dL0);          async16(A  + aS1,       lds + dL1);
  async16(Bt + bS0,       lds + 32768 + dL0);  async16(Bt + bS1,       lds + 32768 + dL1);
  async16(A  + aS0 + 32,  lds + 16384 + dL0);  async16(A  + aS1 + 32,  lds + 16384 + dL1);
  async16(Bt + bS0 + 32,  lds + 49152 + dL0);  async16(Bt + bS1 + 32,  lds + 49152 + dL1);
  async16(A  + aS0 + 64,  lds + 65536 + dL0);  async16(A  + aS1 + 64,  lds + 65536 + dL1);
  async16(Bt + bS0 + 64,  lds + 98304 + dL0);  async16(Bt + bS1 + 64,  lds + 98304 + dL1);
  asm volatile("s_waitcnt vmcnt(4)" ::: "memory");
  __builtin_amdgcn_s_barrier();

  for (int t = 0; t < NT; ++t) {
    char* buf  = lds + (t & 1) * 65536;
    char* nbuf = lds + ((t + 1) & 1) * 65536;
    const size_t kA = (size_t)t * 64;
    const bool s1 = (t + 1 < NT), s2 = (t + 2 < NT);
    s16x8 aR[4], bR[4];

    { // ph0
      const char* ab = buf + afoff;
      const char* bb = buf + bfoff;
#pragma unroll
      for (int i = 0; i < 4; ++i) aR[i] = *(const s16x8*)(ab + i * 1024);
#pragma unroll
      for (int i = 0; i < 4; ++i) bR[i] = *(const s16x8*)(bb + i * 1024);
      if (s1) {
        async16(A + aS0 + kA + 96, nbuf + 16384 + dL0);
        async16(A + aS1 + kA + 96, nbuf + 16384 + dL1);
      }
      __builtin_amdgcn_s_setprio(1);
#pragma unroll
      for (int mf = 0; mf < 4; ++mf)
#pragma unroll
        for (int nf = 0; nf < 4; ++nf)
          acc[mf][nf] = __builtin_amdgcn_mfma_f32_16x16x32_bf16(aR[mf], bR[nf], acc[mf][nf], 0, 0, 0);
      __builtin_amdgcn_s_setprio(0);
      __builtin_amdgcn_s_barrier();
    }
    { // ph1
      const char* ab = buf + afoff + 4096;
#pragma unroll
      for (int i = 0; i < 4; ++i) aR[i] = *(const s16x8*)(ab + i * 1024);
      if (s1) {
        async16(Bt + bS0 + kA + 96, nbuf + 49152 + dL0);
        async16(Bt + bS1 + kA + 96, nbuf + 49152 + dL1);
      }
      __builtin_amdgcn_s_setprio(1);
#pragma unroll
      for (int mf = 0; mf < 4; ++mf)
#pragma unroll
        for (int nf = 0; nf < 4; ++nf)
          acc[4 + mf][nf] = __builtin_amdgcn_mfma_f32_16x16x32_bf16(aR[mf], bR[nf], acc[4 + mf][nf], 0, 0, 0);
      __builtin_amdgcn_s_setprio(0);
      __builtin_amdgcn_s_barrier();
    }
    { // ph2
      const char* ab = buf + 16384 + afoff;
      const char* bb = buf + 16384 + bfoff;
#pragma unroll
      for (int i = 0; i < 4; ++i) aR[i] = *(const s16x8*)(ab + i * 1024);
#pragma unroll
      for (int i = 0; i < 4; ++i) bR[i] = *(const s16x8*)(bb + i * 1024);
      if (s2) {
        async16(A + aS0 + kA + 128, buf + dL0);
        async16(A + aS1 + kA + 128, buf + dL1);
      }
      __builtin_amdgcn_s_setprio(1);
#pragma unroll
      for (int mf = 0; mf < 4; ++mf)
#pragma unroll
        for (int nf = 0; nf < 4; ++nf)
          acc[mf][nf] = __builtin_amdgcn_mfma_f32_16x16x32_bf16(aR[mf], bR[nf], acc[mf][nf], 0, 0, 0);
      __builtin_amdgcn_s_setprio(0);
      __builtin_amdgcn_s_barrier();
    }
    { // ph3
      const char* ab = buf + 16384 + afoff + 4096;
#pragma unroll
      for (int i = 0; i < 4; ++i) aR[i] = *(const s16x8*)(ab + i * 1024);
      if (s2) {
        async16(Bt + bS0 + kA + 128, buf + 32768 + dL0);
        async16(Bt + bS1 + kA + 128, buf + 32768 + dL1);
      }
      __builtin_amdgcn_s_setprio(1);
#pragma unroll
      for (int mf = 0; mf < 4; ++mf)
#pragma unroll
        for (int nf = 0; nf < 4; ++nf)
          acc[4 + mf][nf] = __builtin_amdgcn_mfma_f32_16x16x32_bf16(aR[mf], bR[nf], acc[4 + mf][nf], 0, 0, 0);
      __builtin_amdgcn_s_setprio(0);
      if (t < NT - 2)       { asm volatile("s_waitcnt vmcnt(4)" ::: "memory"); }
      else if (t == NT - 2) { asm volatile("s_waitcnt vmcnt(0)" ::: "memory"); }
      __builtin_amdgcn_s_barrier();
    }
  }

  float bv[4];
#pragma unroll
  for (int n = 0; n < 4; ++n) bv[n] = bias[bn + wn * 64 + n * 16 + li];

  if (MODE == 3 && bn < 4096) {
    // fp8 epilogue -> qk8 [.,4096]
    unsigned char* C8 = (unsigned char*)Cout;
    unsigned char* wl0 = (unsigned char*)(lds + w * 12288);
#pragma unroll
    for (int mp = 0; mp < 4; ++mp) {
      unsigned char* wl = wl0 + (mp & 1) * 2304;
#pragma unroll
      for (int mi = 0; mi < 2; ++mi)
#pragma unroll
        for (int n = 0; n < 4; ++n)
#pragma unroll
          for (int jj = 0; jj < 4; ++jj) {
            float v = acc[mp * 2 + mi][n][jj] + bv[n];
            wl[(mi * 16 + lc * 4 + jj) * 72 + n * 16 + li] = f2e4m3(v);
          }
#pragma unroll
      for (int i = 0; i < 4; ++i) {
        const int rr = i * 8 + (lane >> 3);
        uint2 vv = *(const uint2*)(wl + rr * 72 + (lane & 7) * 8);
        const size_t gi = (size_t)(bm + wm * 128 + mp * 32 + rr) * 4096
                        + bn + wn * 64 + (lane & 7) * 8;
        *(uint2*)(C8 + gi) = vv;
      }
    }
  } else if (MODE == 3) {
    // bf16 epilogue -> vbuf [.,1024]
    unsigned short* Cv = (unsigned short*)const_cast<unsigned short*>(res);
    unsigned short* wl0 = (unsigned short*)(lds + w * 12288);
    const int cb = bn - 4096;
#pragma unroll
    for (int mp = 0; mp < 4; ++mp) {
      unsigned short* wl = wl0 + (mp & 1) * 2304;
#pragma unroll
      for (int mi = 0; mi < 2; ++mi)
#pragma unroll
        for (int n = 0; n < 4; ++n)
#pragma unroll
          for (int jj = 0; jj < 4; ++jj) {
            float v = acc[mp * 2 + mi][n][jj] + bv[n];
            wl[(mi * 16 + lc * 4 + jj) * 72 + li + n * 16] = f2bf(v);
          }
#pragma unroll
      for (int i = 0; i < 4; ++i) {
        const int rr = i * 8 + (lane >> 3);
        u16x8 vv = *(const u16x8*)(wl + rr * 72 + (lane & 7) * 8);
        const size_t gi = (size_t)(bm + wm * 128 + mp * 32 + rr) * 1024
                        + cb + wn * 64 + (lane & 7) * 8;
        *(u16x8*)(Cv + gi) = vv;
      }
    }
  } else {
    // MODE 2: f32 + residual
    float* Cf = (float*)Cout;
    float* wl0 = (float*)(lds + w * 12288);
#pragma unroll
    for (int m = 0; m < 8; ++m) {
      float* wl = wl0 + (m & 1) * 1088;
#pragma unroll
      for (int n = 0; n < 4; ++n)
#pragma unroll
        for (int jj = 0; jj < 4; ++jj)
          wl[(lc * 4 + jj) * 68 + li + n * 16] = acc[m][n][jj] + bv[n];
#pragma unroll
      for (int i = 0; i < 4; ++i) {
        const int rr = i * 4 + lc;
        f32x4 vv = *(const f32x4*)(wl + rr * 68 + li * 4);
        const size_t gi = (size_t)(bm + wm * 128 + m * 16 + rr) * Ndim
                        + bn + wn * 64 + li * 4;
        const u16x4 rv = *(const u16x4*)(res + gi);
        f32x4 ov;
#pragma unroll
        for (int jj = 0; jj < 4; ++jj) ov[jj] = vv[jj] + bf2f(rv[jj]);
        *(f32x4*)(Cf + gi) = ov;
      }
    }
  }
}

// ---------------------------------------------------------------------------
// Lambda hidden GEMM with fused relu-dot epilogue: atomicAdd partial
// relu(x@L1+b1).L2w into lam_pre[row]. No hbuf round trip.
// grid (128, 2), block 256.
// ---------------------------------------------------------------------------
__global__ __launch_bounds__(256, 2)
void gemm_lam(const unsigned short* __restrict__ A,
              const unsigned short* __restrict__ Bt,
              const float* __restrict__ bias,
              const float* __restrict__ L2w,
              float* __restrict__ lam_pre,
              int Kdim)
{
  __shared__ __align__(16) unsigned short lA[128 * 32];
  __shared__ __align__(16) unsigned short lB[128 * 32];
  const int tid  = threadIdx.x;
  const int lane = tid & 63, wid = tid >> 6;
  const int wm = wid >> 1, wn = wid & 1;
  const int bm = blockIdx.x * 128, bn = blockIdx.y * 128;

  f32x4 acc[4][4];
#pragma unroll
  for (int i = 0; i < 4; ++i)
#pragma unroll
    for (int j = 0; j < 4; ++j) acc[i][j] = (f32x4)0.f;

  const int ar = tid >> 2;
  const int ac = (tid & 3) * 8;
  const unsigned short* aG0 = A  + (size_t)(bm + ar) * Kdim + ac;
  const unsigned short* aG1 = aG0 + (size_t)64 * Kdim;
  const unsigned short* bG0 = Bt + (size_t)(bn + ar) * Kdim + ac;
  const unsigned short* bG1 = bG0 + (size_t)64 * Kdim;
  unsigned short* aL0 = lA + wid * 512;
  unsigned short* aL1 = lA + 2048 + wid * 512;
  unsigned short* bL0 = lB + wid * 512;
  unsigned short* bL1 = lB + 2048 + wid * 512;

  const unsigned short* aF = lA + (wm * 64 + (lane & 15)) * 32 + (lane >> 4) * 8;
  const unsigned short* bF = lB + (wn * 64 + (lane & 15)) * 32 + (lane >> 4) * 8;

  for (int k0 = 0; k0 < Kdim; k0 += 32) {
    async16(aG0, aL0); async16(aG1, aL1);
    async16(bG0, bL0); async16(bG1, bL1);
    aG0 += 32; aG1 += 32; bG0 += 32; bG1 += 32;
    __syncthreads();
    s16x8 af[4], bw[4];
#pragma unroll
    for (int m = 0; m < 4; ++m) af[m] = *(const s16x8*)(aF + m * 512);
#pragma unroll
    for (int n = 0; n < 4; ++n) bw[n] = *(const s16x8*)(bF + n * 512);
#pragma unroll
    for (int m = 0; m < 4; ++m)
#pragma unroll
      for (int n = 0; n < 4; ++n)
        acc[m][n] = __builtin_amdgcn_mfma_f32_16x16x32_bf16(af[m], bw[n], acc[m][n], 0, 0, 0);
    __syncthreads();
  }

  // fused epilogue: partial dot with L2w, lane-reduce over li, atomicAdd
  const int r0 = bm + wm * 64 + ((lane >> 4) << 2);
  const int c0 = bn + wn * 64 + (lane & 15);
  float l2v[4], bvv[4];
#pragma unroll
  for (int n = 0; n < 4; ++n) { l2v[n] = L2w[c0 + n * 16]; bvv[n] = bias[c0 + n * 16]; }
#pragma unroll
  for (int m = 0; m < 4; ++m)
#pragma unroll
    for (int j = 0; j < 4; ++j) {
      float part = 0.f;
#pragma unroll
      for (int n = 0; n < 4; ++n)
        part += fmaxf(acc[m][n][j] + bvv[n], 0.f) * l2v[n];
      part += __shfl_xor(part, 1, 64);
      part += __shfl_xor(part, 2, 64);
      part += __shfl_xor(part, 4, 64);
      part += __shfl_xor(part, 8, 64);
      if ((lane & 15) == 0) atomicAdd(lam_pre + r0 + m * 16 + j, part);
    }
}

// ---------------------------------------------------------------------------
// Attention core. qk8 [32768,4096] fp8 (Q1|K1|Q2|K2), vbuf [32768,1024] bf16.
// lam = sigmoid(lam_pre[b] + L2b).
// ---------------------------------------------------------------------------
__global__ __launch_bounds__(256)
void attn_kernel(const unsigned char* __restrict__ qk8,
                 const unsigned short* __restrict__ vbuf,
                 const float* __restrict__ lam_pre,
                 const float* __restrict__ L2b,
                 unsigned short* __restrict__ aout)
{
  const int b = blockIdx.x;
  const int hd = threadIdx.x >> 6;
  const int lane = threadIdx.x & 63;
  const int g = lane >> 5;
  const int l5 = lane & 31;
  const size_t row = (size_t)(2 * b + g);
  const size_t b8 = row * 4096 + hd * 256 + l5 * 8;

  const uint2 p1 = *(const uint2*)(qk8 + b8);
  const uint2 p2 = *(const uint2*)(qk8 + b8 + 1024);
  const uint2 p3 = *(const uint2*)(qk8 + b8 + 2048);
  const uint2 p4 = *(const uint2*)(qk8 + b8 + 3072);
  const u16x8 vvv = *(const u16x8*)(vbuf + row * 1024 + hd * 256 + l5 * 8);

  float q1[8], k1[8], q2[8], k2[8], vf[8];
  dec8(p1, q1); dec8(p2, k1); dec8(p3, q2); dec8(p4, k2);
#pragma unroll
  for (int j = 0; j < 8; ++j) vf[j] = bf2f(vvv[j]);

  float ss1 = 0.f, sc1 = 0.f, ss2 = 0.f, sc2 = 0.f;
#pragma unroll
  for (int j = 0; j < 8; ++j) {
    const float k1o = __shfl_xor(k1[j], 32, 64);
    const float k2o = __shfl_xor(k2[j], 32, 64);
    ss1 += q1[j] * k1[j]; sc1 += q1[j] * k1o;
    ss2 += q2[j] * k2[j]; sc2 += q2[j] * k2o;
  }
#pragma unroll
  for (int m = 16; m >= 1; m >>= 1) {
    ss1 += __shfl_xor(ss1, m, 64); sc1 += __shfl_xor(sc1, m, 64);
    ss2 += __shfl_xor(ss2, m, 64); sc2 += __shfl_xor(sc2, m, 64);
  }

  float e0 = ss1 * ATT_SCALE, e1 = sc1 * ATT_SCALE;
  float mx = fmaxf(e0, e1);
  float xs = expf(e0 - mx), xc = expf(e1 - mx);
  float inv = 1.f / (xs + xc);
  const float a1s = xs * inv, a1c = xc * inv;

  e0 = ss2 * ATT_SCALE; e1 = sc2 * ATT_SCALE;
  mx = fmaxf(e0, e1);
  xs = expf(e0 - mx); xc = expf(e1 - mx);
  inv = 1.f / (xs + xc);
  const float a2s = xs * inv, a2c = xc * inv;

  const float lm = 1.f / (1.f + expf(-(lam_pre[b] + L2b[0])));
  const float ps = fmaxf(a1s - lm * a2s, 0.f);
  const float pc = fmaxf(a1c - lm * a2c, 0.f);

  u16x8 o;
#pragma unroll
  for (int j = 0; j < 8; ++j) {
    const float vo = __shfl_xor(vf[j], 32, 64);
    o[j] = f2bf(ps * vf[j] + pc * vo);
  }
  *(u16x8*)(aout + row * 1024 + hd * 256 + l5 * 8) = o;
}

// ---------------------------------------------------------------------------
// conversions
// ---------------------------------------------------------------------------
__global__ void f32_to_bf16_k(const float* __restrict__ in,
                              unsigned short* __restrict__ out, int n8)
{
  const int i = blockIdx.x * 256 + threadIdx.x;
  if (i >= n8) return;
  const float4* p = (const float4*)in + (size_t)i * 2;
  float4 a = p[0], b = p[1];
  u16x8 v;
  v[0] = f2bf(a.x); v[1] = f2bf(a.y); v[2] = f2bf(a.z); v[3] = f2bf(a.w);
  v[4] = f2bf(b.x); v[5] = f2bf(b.y); v[6] = f2bf(b.z); v[7] = f2bf(b.w);
  *(u16x8*)(out + (size_t)i * 8) = v;
}

// 6x batched: W f32 [1024,1024] -> Wt bf16 transposed (5 -> qw concat, 1 -> wot)
__global__ void transpose6_k(const float* __restrict__ s0, const float* __restrict__ s1,
                             const float* __restrict__ s2, const float* __restrict__ s3,
                             const float* __restrict__ s4, const float* __restrict__ s5,
                             unsigned short* __restrict__ qw,
                             unsigned short* __restrict__ wot)
{
  __shared__ float tile[32][33];
  const float* W; unsigned short* Wt;
  switch (blockIdx.z) {
    case 0: W = s0; Wt = qw;               break;
    case 1: W = s1; Wt = qw + 1048576;     break;
    case 2: W = s2; Wt = qw + 2097152;     break;
    case 3: W = s3; Wt = qw + 3145728;     break;
    case 4: W = s4; Wt = qw + 4194304;     break;
    default: W = s5; Wt = wot;             break;
  }
  const int bn = blockIdx.x * 32, bk = blockIdx.y * 32;
  const int tx = threadIdx.x, ty = threadIdx.y;
#pragma unroll
  for (int i = ty; i < 32; i += 8)
    tile[i][tx] = W[(size_t)(bk + i) * 1024 + bn + tx];
  __syncthreads();
#pragma unroll
  for (int i = ty; i < 32; i += 8)
    Wt[(size_t)(bn + i) * 1024 + bk + tx] = f2bf(tile[tx][i]);
}

// W f32 [K,N] -> Wt bf16 [N,K]
__global__ void transpose_bf16_k(const float* __restrict__ W,
                                 unsigned short* __restrict__ Wt, int K, int N)
{
  __shared__ float tile[32][33];
  const int bn = blockIdx.x * 32, bk = blockIdx.y * 32;
  const int tx = threadIdx.x, ty = threadIdx.y;
#pragma unroll
  for (int i = ty; i < 32; i += 8)
    tile[i][tx] = W[(size_t)(bk + i) * N + bn + tx];
  __syncthreads();
#pragma unroll
  for (int i = ty; i < 32; i += 8)
    Wt[(size_t)(bn + i) * K + bk + tx] = f2bf(tile[tx][i]);
}

__global__ void concat_bias(const float* __restrict__ b0, const float* __restrict__ b1,
                            const float* __restrict__ b2, const float* __restrict__ b3,
                            const float* __restrict__ b4, float* __restrict__ out)
{
  const int i = blockIdx.x * 256 + threadIdx.x;   // 5120 total
  const float* src;
  switch (i >> 10) {
    case 0: src = b0; break;
    case 1: src = b1; break;
    case 2: src = b2; break;
    case 3: src = b3; break;
    default: src = b4; break;
  }
  out[i] = src[i & 1023];
}

// ---------------------------------------------------------------------------
extern "C" void kernel_launch(void* const* d_in, const int* in_sizes, int n_in,
                              void* d_out, int out_size, void* d_ws, size_t ws_size,
                              hipStream_t stream)
{
  const float* x    = (const float*)d_in[0];
  const float* WQ1w = (const float*)d_in[1];  const float* WQ1b = (const float*)d_in[2];
  const float* WK1w = (const float*)d_in[3];  const float* WK1b = (const float*)d_in[4];
  const float* WQ2w = (const float*)d_in[5];  const float* WQ2b = (const float*)d_in[6];
  const float* WK2w = (const float*)d_in[7];  const float* WK2b = (const float*)d_in[8];
  const float* WVw  = (const float*)d_in[9];  const float* WVb  = (const float*)d_in[10];
  const float* WOw  = (const float*)d_in[11]; const float* WOb  = (const float*)d_in[12];
  const float* L1w  = (const float*)d_in[13]; const float* L1b  = (const float*)d_in[14];
  const float* L2w  = (const float*)d_in[15]; const float* L2b  = (const float*)d_in[16];

  char* ws = (char*)d_ws;
  size_t off = 0;
  unsigned short* x_bf = (unsigned short*)(ws + off); off += (size_t)33554432 * 2;   // 64MB
  unsigned short* qw   = (unsigned short*)(ws + off); off += (size_t)5242880 * 2;    // 10MB [5120,1024]
  unsigned short* wot  = (unsigned short*)(ws + off); off += (size_t)1048576 * 2;    // 2MB
  unsigned short* l1t  = (unsigned short*)(ws + off); off += (size_t)524288 * 2;     // 1MB
  float*          bcat = (float*)(ws + off);          off += (size_t)5120 * 4;
  unsigned char*  qk8  = (unsigned char*)(ws + off);  off += (size_t)32768 * 4096;   // 128MB
  unsigned short* vbuf = (unsigned short*)(ws + off); off += (size_t)33554432 * 2;   // 64MB
  unsigned short* abuf = (unsigned short*)(ws + off); off += (size_t)33554432 * 2;   // 64MB
  float*          lamp = (float*)(ws + off);          off += (size_t)16384 * 4;

  // conversions
  f32_to_bf16_k<<<4194304 / 256, 256, 0, stream>>>(x, x_bf, 4194304);
  dim3 tb(32, 8);
  transpose6_k<<<dim3(32, 32, 6), tb, 0, stream>>>(WQ1w, WK1w, WQ2w, WK2w, WVw, WOw, qw, wot);
  transpose_bf16_k<<<dim3(8, 64), tb, 0, stream>>>(L1w, l1t, 2048, 256);
  concat_bias<<<20, 256, 0, stream>>>(WQ1b, WK1b, WQ2b, WK2b, WVb, bcat);

  // lambda net (fused dot via atomics)
  hipMemsetAsync((void*)lamp, 0, 16384 * 4, stream);
  gemm_lam<<<dim3(128, 2), 256, 0, stream>>>(x_bf, l1t, L1b, L2w, lamp, 2048);

  // fused projections: [32768,1024] @ [1024,5120]; Q1K1Q2K2 -> fp8, V -> bf16
  gemm256<3><<<dim3(128 * 20), 512, 0, stream>>>(x_bf, qw, bcat, qk8, vbuf, 1024, 5120, 20);

  // attention core
  attn_kernel<<<16384, 256, 0, stream>>>(qk8, vbuf, lamp, L2b, abuf);

  // output: attn @ WO + bias + residual(x_bf), f32
  gemm256<2><<<dim3(128 * 4), 512, 0, stream>>>(abuf, wot, WOb, d_out, x_bf, 1024, 1024, 4);
}

// Round 9
// 565.852 us; speedup vs baseline: 1.2442x; 1.2286x over previous
//
#include <hip/hip_runtime.h>
#include <stdint.h>

// ---------------------------------------------------------------------------
// AdaptiveDiffAttention on MI355X (gfx950)
// Round 9: r8 + RMW fix. qk8 stored in chunk-blocked layout (32x64 = 2048B
// contiguous per wave sub-tile) -> full-line writes, no read-modify-write.
// HW fp8 cvt builtins (guarded). K-loop = r4 verbatim. Lambda fused (atomics).
// ---------------------------------------------------------------------------

#define BATCH  16384
#define ATT_SCALE 0.0625f // 256^-0.5

typedef __attribute__((ext_vector_type(8)))  short   s16x8;
typedef __attribute__((ext_vector_type(4)))  float   f32x4;
typedef __attribute__((ext_vector_type(2)))  float   f32x2;
typedef __attribute__((ext_vector_type(8)))  unsigned short u16x8;
typedef __attribute__((ext_vector_type(4)))  unsigned short u16x4;

__device__ __forceinline__ unsigned short f2bf(float f) {
  unsigned u = __float_as_uint(f);
  u += 0x7FFFu + ((u >> 16) & 1u);   // RNE
  return (unsigned short)(u >> 16);
}
__device__ __forceinline__ float bf2f(unsigned short s) {
  return __uint_as_float((unsigned)s << 16);
}

// OCP e4m3fn encode/decode (manual fallback, r7/r8-proven)
__device__ __forceinline__ unsigned char f2e4m3(float f) {
  unsigned u = __float_as_uint(f);
  unsigned s = (u >> 24) & 0x80u;
  float a = fabsf(f);
  if (a >= 448.f) return (unsigned char)(s | 0x7E);
  if (a < 0.0009765625f) return (unsigned char)s;
  int e = (int)((u >> 23) & 0xFF) - 127;
  if (e < -6) {
    int q = (int)rintf(a * 512.f);
    if (q >= 8) return (unsigned char)(s | 0x08);
    return (unsigned char)(s | q);
  }
  unsigned mant = u & 0x7FFFFFu;
  unsigned mr = mant + 0x7FFFFu + ((mant >> 20) & 1u);
  e += (int)(mr >> 23);
  mant = (mr >> 20) & 7u;
  if (e > 8) return (unsigned char)(s | 0x7E);
  return (unsigned char)(s | ((e + 7) << 3) | mant);
}
__device__ __forceinline__ float e4m3f(unsigned v) {
  unsigned e = (v >> 3) & 15u, m = v & 7u;
  float mag = (e == 0) ? (float)m * 0.001953125f
                       : __uint_as_float(((e + 120u) << 23) | (m << 20));
  return (v & 0x80u) ? -mag : mag;
}

__device__ __forceinline__ unsigned char cvt1_fp8(float v) {
#if __has_builtin(__builtin_amdgcn_cvt_pk_fp8_f32)
  return (unsigned char)(__builtin_amdgcn_cvt_pk_fp8_f32(v, v, 0, false) & 0xff);
#else
  return f2e4m3(v);
#endif
}

__device__ __forceinline__ void dec8(uint2 p, float* o) {
#if __has_builtin(__builtin_amdgcn_cvt_pk_f32_fp8)
  f32x2 a = __builtin_amdgcn_cvt_pk_f32_fp8((int)p.x, false);
  f32x2 b = __builtin_amdgcn_cvt_pk_f32_fp8((int)p.x, true);
  f32x2 c = __builtin_amdgcn_cvt_pk_f32_fp8((int)p.y, false);
  f32x2 d = __builtin_amdgcn_cvt_pk_f32_fp8((int)p.y, true);
  o[0] = a[0]; o[1] = a[1]; o[2] = b[0]; o[3] = b[1];
  o[4] = c[0]; o[5] = c[1]; o[6] = d[0]; o[7] = d[1];
#else
#pragma unroll
  for (int j = 0; j < 4; ++j) o[j]     = e4m3f((p.x >> (8 * j)) & 255u);
#pragma unroll
  for (int j = 0; j < 4; ++j) o[4 + j] = e4m3f((p.y >> (8 * j)) & 255u);
#endif
}

__device__ __forceinline__ void async16(const void* g, void* l) {
  __builtin_amdgcn_global_load_lds((__attribute__((address_space(1))) void*)g,
                                   (__attribute__((address_space(3))) void*)l,
                                   16, 0, 0);
}

// ---------------------------------------------------------------------------
// 256x256 GEMM: C = A[M,K](bf16) @ Bt[N,K]^T(bf16) + bias. r4 K-loop verbatim.
// MODE 2: +res(bf16), store f32.
// MODE 3: proj split epilogue — bn<4096 -> fp8 chunk-blocked qk8;
//         bn>=4096 -> bf16 row-major vbuf (via res pointer).
// ---------------------------------------------------------------------------
template<int MODE>
__global__ __launch_bounds__(512, 2)
void gemm256(const unsigned short* __restrict__ A,
             const unsigned short* __restrict__ Bt,
             const float* __restrict__ bias,
             void* __restrict__ Cout,
             const unsigned short* __restrict__ res,
             int Kdim, int Ndim, int NN)
{
  __shared__ __align__(16) char lds[131072];
  const int tid  = threadIdx.x;
  const int lane = tid & 63, w = tid >> 6;
  const int wm = w >> 2, wn = w & 3;
  const int li = lane & 15, lc = lane >> 4;

  const int nwg = gridDim.x;
  const int q8 = nwg >> 3, r8 = nwg & 7;
  const int xcd = blockIdx.x & 7, pos = blockIdx.x >> 3;
  const int swz = (xcd < r8 ? xcd * (q8 + 1) : r8 * (q8 + 1) + (xcd - r8) * q8) + pos;
  const int bm = (swz / NN) * 256;
  const int bn = (swz % NN) * 256;

  const int r0  = w * 32 + (lane >> 2);
  const int csw = ((lane & 3) ^ ((r0 >> 1) & 3)) * 8;
  const size_t aS0 = (size_t)(bm + r0) * Kdim + csw;
  const size_t aS1 = (size_t)(bm + r0 + 16) * Kdim + csw;
  const size_t bS0 = (size_t)(bn + r0) * Kdim + csw;
  const size_t bS1 = (size_t)(bn + r0 + 16) * Kdim + csw;
  const int dL0 = w * 2048, dL1 = dL0 + 1024;

  const int fsw   = (lc ^ ((li >> 1) & 3)) << 4;
  const int afoff = (wm * 128 + li) * 64 + fsw;
  const int bfoff = 32768 + (wn * 64 + li) * 64 + fsw;

  f32x4 acc[8][4];
#pragma unroll
  for (int m = 0; m < 8; ++m)
#pragma unroll
    for (int n = 0; n < 4; ++n) acc[m][n] = (f32x4)0.f;

  const int NT = Kdim >> 6;

  async16(A  + aS0,       lds + dL0);          async16(A  + aS1,       lds + dL1);
  async16(Bt + bS0,       lds + 32768 + dL0);  async16(Bt + bS1,       lds + 32768 + dL1);
  async16(A  + aS0 + 32,  lds + 16384 + dL0);  async16(A  + aS1 + 32,  lds + 16384 + dL1);
  async16(Bt + bS0 + 32,  lds + 49152 + dL0);  async16(Bt + bS1 + 32,  lds + 49152 + dL1);
  async16(A  + aS0 + 64,  lds + 65536 + dL0);  async16(A  + aS1 + 64,  lds + 65536 + dL1);
  async16(Bt + bS0 + 64,  lds + 98304 + dL0);  async16(Bt + bS1 + 64,  lds + 98304 + dL1);
  asm volatile("s_waitcnt vmcnt(4)" ::: "memory");
  __builtin_amdgcn_s_barrier();

  for (int t = 0; t < NT; ++t) {
    char* buf  = lds + (t & 1) * 65536;
    char* nbuf = lds + ((t + 1) & 1) * 65536;
    const size_t kA = (size_t)t * 64;
    const bool s1 = (t + 1 < NT), s2 = (t + 2 < NT);
    s16x8 aR[4], bR[4];

    { // ph0
      const char* ab = buf + afoff;
      const char* bb = buf + bfoff;
#pragma unroll
      for (int i = 0; i < 4; ++i) aR[i] = *(const s16x8*)(ab + i * 1024);
#pragma unroll
      for (int i = 0; i < 4; ++i) bR[i] = *(const s16x8*)(bb + i * 1024);
      if (s1) {
        async16(A + aS0 + kA + 96, nbuf + 16384 + dL0);
        async16(A + aS1 + kA + 96, nbuf + 16384 + dL1);
      }
      __builtin_amdgcn_s_setprio(1);
#pragma unroll
      for (int mf = 0; mf < 4; ++mf)
#pragma unroll
        for (int nf = 0; nf < 4; ++nf)
          acc[mf][nf] = __builtin_amdgcn_mfma_f32_16x16x32_bf16(aR[mf], bR[nf], acc[mf][nf], 0, 0, 0);
      __builtin_amdgcn_s_setprio(0);
      __builtin_amdgcn_s_barrier();
    }
    { // ph1
      const char* ab = buf + afoff + 4096;
#pragma unroll
      for (int i = 0; i < 4; ++i) aR[i] = *(const s16x8*)(ab + i * 1024);
      if (s1) {
        async16(Bt + bS0 + kA + 96, nbuf + 49152 + dL0);
        async16(Bt + bS1 + kA + 96, nbuf + 49152 + dL1);
      }
      __builtin_amdgcn_s_setprio(1);
#pragma unroll
      for (int mf = 0; mf < 4; ++mf)
#pragma unroll
        for (int nf = 0; nf < 4; ++nf)
          acc[4 + mf][nf] = __builtin_amdgcn_mfma_f32_16x16x32_bf16(aR[mf], bR[nf], acc[4 + mf][nf], 0, 0, 0);
      __builtin_amdgcn_s_setprio(0);
      __builtin_amdgcn_s_barrier();
    }
    { // ph2
      const char* ab = buf + 16384 + afoff;
      const char* bb = buf + 16384 + bfoff;
#pragma unroll
      for (int i = 0; i < 4; ++i) aR[i] = *(const s16x8*)(ab + i * 1024);
#pragma unroll
      for (int i = 0; i < 4; ++i) bR[i] = *(const s16x8*)(bb + i * 1024);
      if (s2) {
        async16(A + aS0 + kA + 128, buf + dL0);
        async16(A + aS1 + kA + 128, buf + dL1);
      }
      __builtin_amdgcn_s_setprio(1);
#pragma unroll
      for (int mf = 0; mf < 4; ++mf)
#pragma unroll
        for (int nf = 0; nf < 4; ++nf)
          acc[mf][nf] = __builtin_amdgcn_mfma_f32_16x16x32_bf16(aR[mf], bR[nf], acc[mf][nf], 0, 0, 0);
      __builtin_amdgcn_s_setprio(0);
      __builtin_amdgcn_s_barrier();
    }
    { // ph3
      const char* ab = buf + 16384 + afoff + 4096;
#pragma unroll
      for (int i = 0; i < 4; ++i) aR[i] = *(const s16x8*)(ab + i * 1024);
      if (s2) {
        async16(Bt + bS0 + kA + 128, buf + 32768 + dL0);
        async16(Bt + bS1 + kA + 128, buf + 32768 + dL1);
      }
      __builtin_amdgcn_s_setprio(1);
#pragma unroll
      for (int mf = 0; mf < 4; ++mf)
#pragma unroll
        for (int nf = 0; nf < 4; ++nf)
          acc[4 + mf][nf] = __builtin_amdgcn_mfma_f32_16x16x32_bf16(aR[mf], bR[nf], acc[4 + mf][nf], 0, 0, 0);
      __builtin_amdgcn_s_setprio(0);
      if (t < NT - 2)       { asm volatile("s_waitcnt vmcnt(4)" ::: "memory"); }
      else if (t == NT - 2) { asm volatile("s_waitcnt vmcnt(0)" ::: "memory"); }
      __builtin_amdgcn_s_barrier();
    }
  }

  float bv[4];
#pragma unroll
  for (int n = 0; n < 4; ++n) bv[n] = bias[bn + wn * 64 + n * 16 + li];

  if (MODE == 3 && bn < 4096) {
    // fp8 chunk-blocked epilogue -> qk8. Chunk = 32 rows x 64 cols = 2048B
    // contiguous at ((row>>5)*64 + (col>>6)) * 2048 + (row&31)*64 + (col&63).
    unsigned char* C8 = (unsigned char*)Cout;
    unsigned char* wl0 = (unsigned char*)(lds + w * 12288);
#pragma unroll
    for (int mp = 0; mp < 4; ++mp) {
      unsigned char* wl = wl0 + (mp & 1) * 2560;   // 32 rows x 80B (16-aligned)
#pragma unroll
      for (int mi = 0; mi < 2; ++mi)
#pragma unroll
        for (int n = 0; n < 4; ++n)
#pragma unroll
          for (int jj = 0; jj < 4; ++jj) {
            float v = acc[mp * 2 + mi][n][jj] + bv[n];
            wl[(mi * 16 + lc * 4 + jj) * 80 + n * 16 + li] = cvt1_fp8(v);
          }
      const size_t base = (size_t)((bm + wm * 128 + mp * 32) >> 5) * 131072
                        + (size_t)((bn >> 6) + wn) * 2048;
      uint4 v0 = *(const uint4*)(wl + (lane >> 2) * 80 + (lane & 3) * 16);
      *(uint4*)(C8 + base + lane * 16) = v0;
      uint4 v1 = *(const uint4*)(wl + (16 + (lane >> 2)) * 80 + (lane & 3) * 16);
      *(uint4*)(C8 + base + 1024 + lane * 16) = v1;
    }
  } else if (MODE == 3) {
    // bf16 epilogue -> vbuf [.,1024]
    unsigned short* Cv = (unsigned short*)const_cast<unsigned short*>(res);
    unsigned short* wl0 = (unsigned short*)(lds + w * 12288);
    const int cb = bn - 4096;
#pragma unroll
    for (int mp = 0; mp < 4; ++mp) {
      unsigned short* wl = wl0 + (mp & 1) * 2304;
#pragma unroll
      for (int mi = 0; mi < 2; ++mi)
#pragma unroll
        for (int n = 0; n < 4; ++n)
#pragma unroll
          for (int jj = 0; jj < 4; ++jj) {
            float v = acc[mp * 2 + mi][n][jj] + bv[n];
            wl[(mi * 16 + lc * 4 + jj) * 72 + li + n * 16] = f2bf(v);
          }
#pragma unroll
      for (int i = 0; i < 4; ++i) {
        const int rr = i * 8 + (lane >> 3);
        u16x8 vv = *(const u16x8*)(wl + rr * 72 + (lane & 7) * 8);
        const size_t gi = (size_t)(bm + wm * 128 + mp * 32 + rr) * 1024
                        + cb + wn * 64 + (lane & 7) * 8;
        *(u16x8*)(Cv + gi) = vv;
      }
    }
  } else {
    // MODE 2: f32 + residual
    float* Cf = (float*)Cout;
    float* wl0 = (float*)(lds + w * 12288);
#pragma unroll
    for (int m = 0; m < 8; ++m) {
      float* wl = wl0 + (m & 1) * 1088;
#pragma unroll
      for (int n = 0; n < 4; ++n)
#pragma unroll
        for (int jj = 0; jj < 4; ++jj)
          wl[(lc * 4 + jj) * 68 + li + n * 16] = acc[m][n][jj] + bv[n];
#pragma unroll
      for (int i = 0; i < 4; ++i) {
        const int rr = i * 4 + lc;
        f32x4 vv = *(const f32x4*)(wl + rr * 68 + li * 4);
        const size_t gi = (size_t)(bm + wm * 128 + m * 16 + rr) * Ndim
                        + bn + wn * 64 + li * 4;
        const u16x4 rv = *(const u16x4*)(res + gi);
        f32x4 ov;
#pragma unroll
        for (int jj = 0; jj < 4; ++jj) ov[jj] = vv[jj] + bf2f(rv[jj]);
        *(f32x4*)(Cf + gi) = ov;
      }
    }
  }
}

// ---------------------------------------------------------------------------
// Lambda hidden GEMM with fused relu-dot epilogue (atomicAdd into lam_pre).
// ---------------------------------------------------------------------------
__global__ __launch_bounds__(256, 2)
void gemm_lam(const unsigned short* __restrict__ A,
              const unsigned short* __restrict__ Bt,
              const float* __restrict__ bias,
              const float* __restrict__ L2w,
              float* __restrict__ lam_pre,
              int Kdim)
{
  __shared__ __align__(16) unsigned short lA[128 * 32];
  __shared__ __align__(16) unsigned short lB[128 * 32];
  const int tid  = threadIdx.x;
  const int lane = tid & 63, wid = tid >> 6;
  const int wm = wid >> 1, wn = wid & 1;
  const int bm = blockIdx.x * 128, bn = blockIdx.y * 128;

  f32x4 acc[4][4];
#pragma unroll
  for (int i = 0; i < 4; ++i)
#pragma unroll
    for (int j = 0; j < 4; ++j) acc[i][j] = (f32x4)0.f;

  const int ar = tid >> 2;
  const int ac = (tid & 3) * 8;
  const unsigned short* aG0 = A  + (size_t)(bm + ar) * Kdim + ac;
  const unsigned short* aG1 = aG0 + (size_t)64 * Kdim;
  const unsigned short* bG0 = Bt + (size_t)(bn + ar) * Kdim + ac;
  const unsigned short* bG1 = bG0 + (size_t)64 * Kdim;
  unsigned short* aL0 = lA + wid * 512;
  unsigned short* aL1 = lA + 2048 + wid * 512;
  unsigned short* bL0 = lB + wid * 512;
  unsigned short* bL1 = lB + 2048 + wid * 512;

  const unsigned short* aF = lA + (wm * 64 + (lane & 15)) * 32 + (lane >> 4) * 8;
  const unsigned short* bF = lB + (wn * 64 + (lane & 15)) * 32 + (lane >> 4) * 8;

  for (int k0 = 0; k0 < Kdim; k0 += 32) {
    async16(aG0, aL0); async16(aG1, aL1);
    async16(bG0, bL0); async16(bG1, bL1);
    aG0 += 32; aG1 += 32; bG0 += 32; bG1 += 32;
    __syncthreads();
    s16x8 af[4], bw[4];
#pragma unroll
    for (int m = 0; m < 4; ++m) af[m] = *(const s16x8*)(aF + m * 512);
#pragma unroll
    for (int n = 0; n < 4; ++n) bw[n] = *(const s16x8*)(bF + n * 512);
#pragma unroll
    for (int m = 0; m < 4; ++m)
#pragma unroll
      for (int n = 0; n < 4; ++n)
        acc[m][n] = __builtin_amdgcn_mfma_f32_16x16x32_bf16(af[m], bw[n], acc[m][n], 0, 0, 0);
    __syncthreads();
  }

  const int r0 = bm + wm * 64 + ((lane >> 4) << 2);
  const int c0 = bn + wn * 64 + (lane & 15);
  float l2v[4], bvv[4];
#pragma unroll
  for (int n = 0; n < 4; ++n) { l2v[n] = L2w[c0 + n * 16]; bvv[n] = bias[c0 + n * 16]; }
#pragma unroll
  for (int m = 0; m < 4; ++m)
#pragma unroll
    for (int j = 0; j < 4; ++j) {
      float part = 0.f;
#pragma unroll
      for (int n = 0; n < 4; ++n)
        part += fmaxf(acc[m][n][j] + bvv[n], 0.f) * l2v[n];
      part += __shfl_xor(part, 1, 64);
      part += __shfl_xor(part, 2, 64);
      part += __shfl_xor(part, 4, 64);
      part += __shfl_xor(part, 8, 64);
      if ((lane & 15) == 0) atomicAdd(lam_pre + r0 + m * 16 + j, part);
    }
}

// ---------------------------------------------------------------------------
// Attention core. qk8 chunk-blocked fp8 (Q1|K1|Q2|K2 = chunk col-groups of 16),
// vbuf [32768,1024] bf16. lam = sigmoid(lam_pre[b] + L2b).
// ---------------------------------------------------------------------------
__global__ __launch_bounds__(256)
void attn_kernel(const unsigned char* __restrict__ qk8,
                 const unsigned short* __restrict__ vbuf,
                 const float* __restrict__ lam_pre,
                 const float* __restrict__ L2b,
                 unsigned short* __restrict__ aout)
{
  const int b = blockIdx.x;
  const int hd = threadIdx.x >> 6;
  const int lane = threadIdx.x & 63;
  const int g = lane >> 5;
  const int l5 = lane & 31;
  const size_t row = (size_t)(2 * b + g);

  const size_t cbase = (row >> 5) * 131072
                     + (size_t)(hd * 4 + (l5 >> 3)) * 2048
                     + (row & 31) * 64 + (l5 & 7) * 8;
  const uint2 p1 = *(const uint2*)(qk8 + cbase);
  const uint2 p2 = *(const uint2*)(qk8 + cbase + 32768);
  const uint2 p3 = *(const uint2*)(qk8 + cbase + 65536);
  const uint2 p4 = *(const uint2*)(qk8 + cbase + 98304);
  const u16x8 vvv = *(const u16x8*)(vbuf + row * 1024 + hd * 256 + l5 * 8);

  float q1[8], k1[8], q2[8], k2[8], vf[8];
  dec8(p1, q1); dec8(p2, k1); dec8(p3, q2); dec8(p4, k2);
#pragma unroll
  for (int j = 0; j < 8; ++j) vf[j] = bf2f(vvv[j]);

  float ss1 = 0.f, sc1 = 0.f, ss2 = 0.f, sc2 = 0.f;
#pragma unroll
  for (int j = 0; j < 8; ++j) {
    const float k1o = __shfl_xor(k1[j], 32, 64);
    const float k2o = __shfl_xor(k2[j], 32, 64);
    ss1 += q1[j] * k1[j]; sc1 += q1[j] * k1o;
    ss2 += q2[j] * k2[j]; sc2 += q2[j] * k2o;
  }
#pragma unroll
  for (int m = 16; m >= 1; m >>= 1) {
    ss1 += __shfl_xor(ss1, m, 64); sc1 += __shfl_xor(sc1, m, 64);
    ss2 += __shfl_xor(ss2, m, 64); sc2 += __shfl_xor(sc2, m, 64);
  }

  float e0 = ss1 * ATT_SCALE, e1 = sc1 * ATT_SCALE;
  float mx = fmaxf(e0, e1);
  float xs = expf(e0 - mx), xc = expf(e1 - mx);
  float inv = 1.f / (xs + xc);
  const float a1s = xs * inv, a1c = xc * inv;

  e0 = ss2 * ATT_SCALE; e1 = sc2 * ATT_SCALE;
  mx = fmaxf(e0, e1);
  xs = expf(e0 - mx); xc = expf(e1 - mx);
  inv = 1.f / (xs + xc);
  const float a2s = xs * inv, a2c = xc * inv;

  const float lm = 1.f / (1.f + expf(-(lam_pre[b] + L2b[0])));
  const float ps = fmaxf(a1s - lm * a2s, 0.f);
  const float pc = fmaxf(a1c - lm * a2c, 0.f);

  u16x8 o;
#pragma unroll
  for (int j = 0; j < 8; ++j) {
    const float vo = __shfl_xor(vf[j], 32, 64);
    o[j] = f2bf(ps * vf[j] + pc * vo);
  }
  *(u16x8*)(aout + row * 1024 + hd * 256 + l5 * 8) = o;
}

// ---------------------------------------------------------------------------
// conversions
// ---------------------------------------------------------------------------
__global__ void f32_to_bf16_k(const float* __restrict__ in,
                              unsigned short* __restrict__ out, int n8)
{
  const int i = blockIdx.x * 256 + threadIdx.x;
  if (i >= n8) return;
  const float4* p = (const float4*)in + (size_t)i * 2;
  float4 a = p[0], b = p[1];
  u16x8 v;
  v[0] = f2bf(a.x); v[1] = f2bf(a.y); v[2] = f2bf(a.z); v[3] = f2bf(a.w);
  v[4] = f2bf(b.x); v[5] = f2bf(b.y); v[6] = f2bf(b.z); v[7] = f2bf(b.w);
  *(u16x8*)(out + (size_t)i * 8) = v;
}

// 6x batched: W f32 [1024,1024] -> Wt bf16 transposed (5 -> qw concat, 1 -> wot)
__global__ void transpose6_k(const float* __restrict__ s0, const float* __restrict__ s1,
                             const float* __restrict__ s2, const float* __restrict__ s3,
                             const float* __restrict__ s4, const float* __restrict__ s5,
                             unsigned short* __restrict__ qw,
                             unsigned short* __restrict__ wot)
{
  __shared__ float tile[32][33];
  const float* W; unsigned short* Wt;
  switch (blockIdx.z) {
    case 0: W = s0; Wt = qw;               break;
    case 1: W = s1; Wt = qw + 1048576;     break;
    case 2: W = s2; Wt = qw + 2097152;     break;
    case 3: W = s3; Wt = qw + 3145728;     break;
    case 4: W = s4; Wt = qw + 4194304;     break;
    default: W = s5; Wt = wot;             break;
  }
  const int bn = blockIdx.x * 32, bk = blockIdx.y * 32;
  const int tx = threadIdx.x, ty = threadIdx.y;
#pragma unroll
  for (int i = ty; i < 32; i += 8)
    tile[i][tx] = W[(size_t)(bk + i) * 1024 + bn + tx];
  __syncthreads();
#pragma unroll
  for (int i = ty; i < 32; i += 8)
    Wt[(size_t)(bn + i) * 1024 + bk + tx] = f2bf(tile[tx][i]);
}

// W f32 [K,N] -> Wt bf16 [N,K]
__global__ void transpose_bf16_k(const float* __restrict__ W,
                                 unsigned short* __restrict__ Wt, int K, int N)
{
  __shared__ float tile[32][33];
  const int bn = blockIdx.x * 32, bk = blockIdx.y * 32;
  const int tx = threadIdx.x, ty = threadIdx.y;
#pragma unroll
  for (int i = ty; i < 32; i += 8)
    tile[i][tx] = W[(size_t)(bk + i) * N + bn + tx];
  __syncthreads();
#pragma unroll
  for (int i = ty; i < 32; i += 8)
    Wt[(size_t)(bn + i) * K + bk + tx] = f2bf(tile[tx][i]);
}

__global__ void concat_bias(const float* __restrict__ b0, const float* __restrict__ b1,
                            const float* __restrict__ b2, const float* __restrict__ b3,
                            const float* __restrict__ b4, float* __restrict__ out)
{
  const int i = blockIdx.x * 256 + threadIdx.x;   // 5120 total
  const float* src;
  switch (i >> 10) {
    case 0: src = b0; break;
    case 1: src = b1; break;
    case 2: src = b2; break;
    case 3: src = b3; break;
    default: src = b4; break;
  }
  out[i] = src[i & 1023];
}

// ---------------------------------------------------------------------------
extern "C" void kernel_launch(void* const* d_in, const int* in_sizes, int n_in,
                              void* d_out, int out_size, void* d_ws, size_t ws_size,
                              hipStream_t stream)
{
  const float* x    = (const float*)d_in[0];
  const float* WQ1w = (const float*)d_in[1];  const float* WQ1b = (const float*)d_in[2];
  const float* WK1w = (const float*)d_in[3];  const float* WK1b = (const float*)d_in[4];
  const float* WQ2w = (const float*)d_in[5];  const float* WQ2b = (const float*)d_in[6];
  const float* WK2w = (const float*)d_in[7];  const float* WK2b = (const float*)d_in[8];
  const float* WVw  = (const float*)d_in[9];  const float* WVb  = (const float*)d_in[10];
  const float* WOw  = (const float*)d_in[11]; const float* WOb  = (const float*)d_in[12];
  const float* L1w  = (const float*)d_in[13]; const float* L1b  = (const float*)d_in[14];
  const float* L2w  = (const float*)d_in[15]; const float* L2b  = (const float*)d_in[16];

  char* ws = (char*)d_ws;
  size_t off = 0;
  unsigned short* x_bf = (unsigned short*)(ws + off); off += (size_t)33554432 * 2;   // 64MB
  unsigned short* qw   = (unsigned short*)(ws + off); off += (size_t)5242880 * 2;    // 10MB
  unsigned short* wot  = (unsigned short*)(ws + off); off += (size_t)1048576 * 2;    // 2MB
  unsigned short* l1t  = (unsigned short*)(ws + off); off += (size_t)524288 * 2;     // 1MB
  float*          bcat = (float*)(ws + off);          off += (size_t)5120 * 4;
  unsigned char*  qk8  = (unsigned char*)(ws + off);  off += (size_t)32768 * 4096;   // 128MB
  unsigned short* vbuf = (unsigned short*)(ws + off); off += (size_t)33554432 * 2;   // 64MB
  unsigned short* abuf = (unsigned short*)(ws + off); off += (size_t)33554432 * 2;   // 64MB
  float*          lamp = (float*)(ws + off);          off += (size_t)16384 * 4;

  // conversions
  f32_to_bf16_k<<<4194304 / 256, 256, 0, stream>>>(x, x_bf, 4194304);
  dim3 tb(32, 8);
  transpose6_k<<<dim3(32, 32, 6), tb, 0, stream>>>(WQ1w, WK1w, WQ2w, WK2w, WVw, WOw, qw, wot);
  transpose_bf16_k<<<dim3(8, 64), tb, 0, stream>>>(L1w, l1t, 2048, 256);
  concat_bias<<<20, 256, 0, stream>>>(WQ1b, WK1b, WQ2b, WK2b, WVb, bcat);

  // lambda net (fused dot via atomics)
  hipMemsetAsync((void*)lamp, 0, 16384 * 4, stream);
  gemm_lam<<<dim3(128, 2), 256, 0, stream>>>(x_bf, l1t, L1b, L2w, lamp, 2048);

  // fused projections: [32768,1024] @ [1024,5120]; Q1K1Q2K2 -> fp8 chunked, V -> bf16
  gemm256<3><<<dim3(128 * 20), 512, 0, stream>>>(x_bf, qw, bcat, qk8, vbuf, 1024, 5120, 20);

  // attention core
  attn_kernel<<<16384, 256, 0, stream>>>(qk8, vbuf, lamp, L2b, abuf);

  // output: attn @ WO + bias + residual(x_bf), f32
  gemm256<2><<<dim3(128 * 4), 512, 0, stream>>>(abuf, wot, WOb, d_out, x_bf, 1024, 1024, 4);
}